// Round 7
// baseline (91.622 us; speedup 1.0000x reference)
//
#include <hip/hip_runtime.h>

#define NBINS 100
#define NATOM 1024
#define NBLK  256
#define NWAVE 16
#define HPAD  124            // 3 under + 100 bins + 21 over: no bound checks needed
#define WIN   8              // ±4 sigma window (sigma == bin spacing); tail < 3.4e-4 rel
#define MAGIC 0x5ca1ab1eu
#define PI_F 3.14159265358979323846f

// Single fused kernel, 256 blocks x 1024 threads.
// Phase 1 (all blocks): windowed Gaussian smear into per-wave LDS hists,
//   block partials -> pw[bin*NBLK + blk], device-release + flag[blk]=MAGIC.
// Phase 2 (block 0): spin until all 256 flags==MAGIC (poison-proof: exact match
//   only; flags reset to 0 each call for the next graph replay), acquire fence,
//   reduce partials, normalize, emit count[100] | bins[101] | rdf[100].
// All blocks co-resident (256 blocks <= 256 CUs) -> spin cannot deadlock.
__global__ __launch_bounds__(1024) void rdf_fused(const float* __restrict__ xyz,
                                                  const float* __restrict__ cell,
                                                  float* __restrict__ out,
                                                  float* __restrict__ ws) {
    unsigned* flags = (unsigned*)ws;          // ws[0..255]
    float*    pw    = ws + NBLK;              // partials: pw[bin*NBLK + blk]

    const float cx = cell[0], cy = cell[1], cz = cell[2];
    const float hx = 0.5f * cx, hy = 0.5f * cy, hz = 0.5f * cz;
    const float coeff  = -0.5f * (99.0f * 99.0f) / (5.0f * 5.0f);  // -196.02
    const float cutsq  = 5.5f * 5.5f;
    const float DB     = 5.0f / 99.0f;
    const float INV_DB = 99.0f / 5.0f;

    __shared__ float shw[NWAVE][HPAD];
    for (int k = threadIdx.x; k < NWAVE * HPAD; k += 1024)
        (&shw[0][0])[k] = 0.0f;
    __syncthreads();

    const int wave = threadIdx.x >> 6;

    // thread owns atom j (coalesced load)
    const int j = threadIdx.x;
    const float xj = xyz[3 * j + 0];
    const float yj = xyz[3 * j + 1];
    const float zj = xyz[3 * j + 2];

    const int i0 = blockIdx.x * (NATOM / NBLK);
#pragma unroll
    for (int r = 0; r < NATOM / NBLK; ++r) {
        const int i = i0 + r;                 // block-uniform -> scalar loads
        const float xi = xyz[3 * i + 0];
        const float yi = xyz[3 * i + 1];
        const float zi = xyz[3 * i + 2];
        float dx = xj - xi;                   // dvec = xyz[j] - xyz[i]
        float dy = yj - yi;
        float dz = zj - zi;
        // minimum-image PBC, exact replication of reference shift rule
        dx += (dx < -hx ? cx : 0.0f) - (dx >= hx ? cx : 0.0f);
        dy += (dy < -hy ? cy : 0.0f) - (dy >= hy ? cy : 0.0f);
        dz += (dz < -hz ? cz : 0.0f) - (dz >= hz ? cz : 0.0f);
        const float dsq = dx * dx + dy * dy + dz * dz;
        if (dsq != 0.0f && dsq < cutsq) {
            const float d    = sqrtf(dsq);
            const int   base = (int)(d * INV_DB) - 3;   // window [base, base+7]
            const float t0   = d - (float)base * DB;
            float* h = &shw[wave][base + 3];            // base+3 in [0, 108]
#pragma unroll
            for (int k = 0; k < WIN; ++k) {
                const float t = t0 - (float)k * DB;     // k*DB folds to a constant
                atomicAdd(&h[k], __expf(coeff * t * t));
            }
        }
    }

    __syncthreads();
    if (threadIdx.x < NBINS) {
        float s = 0.0f;
#pragma unroll
        for (int w = 0; w < NWAVE; ++w) s += shw[w][threadIdx.x + 3];
        pw[threadIdx.x * NBLK + blockIdx.x] = s;
    }
    __threadfence();                          // device-scope release of partials
    __syncthreads();
    if (threadIdx.x == 0) atomicExch(&flags[blockIdx.x], MAGIC);

    if (blockIdx.x != 0) return;

    // ---- phase 2: block 0 only ----
    const int t = threadIdx.x;
    if (t < NBLK) {
        // bounded spin: exact-match on MAGIC is poison-proof (0xAAAAAAAA != MAGIC)
        long spin = 0;
        while (atomicAdd(&flags[t], 0u) != MAGIC && spin < (1L << 31)) {
            ++spin;
            __builtin_amdgcn_s_sleep(2);
        }
        flags[t] = 0u;                        // reset for next graph replay
    }
    __threadfence();                          // acquire: no stale partials
    __syncthreads();

    __shared__ float tot[NBINS];
    __shared__ float wsum[2];
    if (t < 8 * NBINS) {                      // 8 threads per bin
        const int b = t >> 3, sub = t & 7;
        const float4* p = (const float4*)&pw[b * NBLK + sub * 32];
        float4 a0 = p[0], a1 = p[1], a2 = p[2], a3 = p[3];
        float4 a4 = p[4], a5 = p[5], a6 = p[6], a7 = p[7];
        float s = ((a0.x + a0.y + a0.z + a0.w) + (a1.x + a1.y + a1.z + a1.w))
                + ((a2.x + a2.y + a2.z + a2.w) + (a3.x + a3.y + a3.z + a3.w))
                + ((a4.x + a4.y + a4.z + a4.w) + (a5.x + a5.y + a5.z + a5.w))
                + ((a6.x + a6.y + a6.z + a6.w) + (a7.x + a7.y + a7.z + a7.w));
        s += __shfl_xor(s, 1, 64);            // butterfly within the 8-lane group
        s += __shfl_xor(s, 2, 64);
        s += __shfl_xor(s, 4, 64);
        if (sub == 0) tot[b] = s;
    }
    __syncthreads();

    const float v = (t < NBINS) ? tot[t] : 0.0f;
    if (t < 128) {
        float s = v;
        s += __shfl_xor(s, 1, 64);
        s += __shfl_xor(s, 2, 64);
        s += __shfl_xor(s, 4, 64);
        s += __shfl_xor(s, 8, 64);
        s += __shfl_xor(s, 16, 64);
        s += __shfl_xor(s, 32, 64);
        if ((t & 63) == 0) wsum[t >> 6] = s;
    }
    __syncthreads();
    const float total = wsum[0] + wsum[1];

    if (t < NBINS) {
        const float count = v / total;
        out[t] = count;                                   // output 0: count[100]
        const float b0 = 0.05f * (float)t;
        const float b1 = 0.05f * (float)(t + 1);
        const float vol = (4.0f * PI_F / 3.0f) * (b1 * b1 * b1 - b0 * b0 * b0);
        const float V = (4.0f / 3.0f) * PI_F * 125.0f;    // end^3 = 5^3
        out[2 * NBINS + 1 + t] = count * V / vol;         // output 2: rdf[100]
    }
    if (t < NBINS + 1) {
        out[NBINS + t] = 0.05f * (float)t;                // output 1: bins[101]
    }
}

extern "C" void kernel_launch(void* const* d_in, const int* in_sizes, int n_in,
                              void* d_out, int out_size, void* d_ws, size_t ws_size,
                              hipStream_t stream) {
    const float* xyz  = (const float*)d_in[0];
    const float* cell = (const float*)d_in[1];
    float* out = (float*)d_out;
    float* ws  = (float*)d_ws;

    rdf_fused<<<NBLK, 1024, 0, stream>>>(xyz, cell, out, ws);
}

// Round 8
// 21.717 us; speedup vs baseline: 4.2190x; 4.2190x over previous
//
#include <hip/hip_runtime.h>

#define NBINS 100
#define NATOM 1024
#define NBLK  256
#define NWAVE 16
#define HPAD  124            // 3 under + 100 bins + 21 over: no bound checks needed
#define WIN   8              // ±4 sigma window (sigma == bin spacing); tail < 3.4e-4 rel
#define QCAP  256            // 4 rows x 64 lanes max passing per wave
#define PI_F 3.14159265358979323846f

// 256 blocks x 1024 threads; block handles rows i0..i0+3, thread owns column j.
// Phase A: dense PBC distance for 4 rows; passing dsq compacted into a per-wave
//   LDS queue via ballot/prefix (same-wave, no barrier needed).
// Phase B: drain queue 64-at-a-time -> window loop runs with ~full lanes
//   (vs ~13/64 active in the branchy form). 8 exps + 8 ds_add per pair.
// Per-wave padded hists (no bound checks); block partials -> ws[bin*NBLK+blk].
// 2-node pipeline: grid-wide sync costs 60-100us on this chip (R3/R7) - avoid.
__global__ __launch_bounds__(1024) void rdf_hist(const float* __restrict__ xyz,
                                                 const float* __restrict__ cell,
                                                 float* __restrict__ ws) {
    const float cx = cell[0], cy = cell[1], cz = cell[2];
    const float hx = 0.5f * cx, hy = 0.5f * cy, hz = 0.5f * cz;
    const float coeff  = -0.5f * (99.0f * 99.0f) / (5.0f * 5.0f);  // -196.02
    const float cutsq  = 5.5f * 5.5f;
    const float DB     = 5.0f / 99.0f;
    const float INV_DB = 99.0f / 5.0f;

    __shared__ float shw[NWAVE][HPAD];
    __shared__ float qd[NWAVE][QCAP];
    for (int k = threadIdx.x; k < NWAVE * HPAD; k += 1024)
        (&shw[0][0])[k] = 0.0f;
    __syncthreads();

    const int wave = threadIdx.x >> 6;
    const int lane = threadIdx.x & 63;
    const unsigned long long ltmask = (1ULL << lane) - 1ULL;

    // thread owns atom j (coalesced load)
    const int j = threadIdx.x;
    const float xj = xyz[3 * j + 0];
    const float yj = xyz[3 * j + 1];
    const float zj = xyz[3 * j + 2];

    // ---- phase A: compact passing pairs into the per-wave queue ----
    int qcount = 0;                           // wave-uniform (ballot-derived)
    const int i0 = blockIdx.x * (NATOM / NBLK);
#pragma unroll
    for (int r = 0; r < NATOM / NBLK; ++r) {
        const int i = i0 + r;                 // block-uniform -> scalar loads
        const float xi = xyz[3 * i + 0];
        const float yi = xyz[3 * i + 1];
        const float zi = xyz[3 * i + 2];
        float dx = xj - xi;                   // dvec = xyz[j] - xyz[i]
        float dy = yj - yi;
        float dz = zj - zi;
        // minimum-image PBC, exact replication of reference shift rule
        dx += (dx < -hx ? cx : 0.0f) - (dx >= hx ? cx : 0.0f);
        dy += (dy < -hy ? cy : 0.0f) - (dy >= hy ? cy : 0.0f);
        dz += (dz < -hz ? cz : 0.0f) - (dz >= hz ? cz : 0.0f);
        const float dsq = dx * dx + dy * dy + dz * dz;
        const bool pass = (dsq != 0.0f) && (dsq < cutsq);
        const unsigned long long b = __ballot(pass);
        if (pass) qd[wave][qcount + __popcll(b & ltmask)] = dsq;
        qcount += __popcll(b);
    }

    // ---- phase B: drain queue with full lanes ----
    const int iters = (qcount + 63) >> 6;
    for (int it = 0; it < iters; ++it) {      // wave-uniform trip count
        const int idx = (it << 6) + lane;
        const bool v = idx < qcount;
        float dsq = qd[wave][idx & (QCAP - 1)];
        dsq = v ? dsq : 1.0f;                 // keep math sane for masked lanes
        const float d    = sqrtf(dsq);
        const int   base = (int)(d * INV_DB) - 3;   // window [base, base+7]
        const float t0   = d - (float)base * DB;
        float* h = &shw[wave][base + 3];            // base+3 in [0, 108]
        if (v) {
#pragma unroll
            for (int k = 0; k < WIN; ++k) {
                const float t = t0 - (float)k * DB; // k*DB folds to a constant
                atomicAdd(&h[k], __expf(coeff * t * t));
            }
        }
    }

    __syncthreads();
    if (threadIdx.x < NBINS) {
        float s = 0.0f;
#pragma unroll
        for (int w = 0; w < NWAVE; ++w) s += shw[w][threadIdx.x + 3];
        // bin-major partial store: finalize's loads over blocks are coalesced
        ws[threadIdx.x * NBLK + blockIdx.x] = s;
    }
}

// single block, 1024 threads: reduce 256 partials/bin, normalize, emit outputs
__global__ __launch_bounds__(1024) void rdf_finalize(const float* __restrict__ ws,
                                                     float* __restrict__ out) {
    __shared__ float tot[NBINS];
    __shared__ float wsum[2];

    const int t = threadIdx.x;
    if (t < 8 * NBINS) {             // 8 threads per bin
        const int b = t >> 3, sub = t & 7;
        const float4* p = (const float4*)&ws[b * NBLK + sub * 32];
        float4 a0 = p[0], a1 = p[1], a2 = p[2], a3 = p[3];
        float4 a4 = p[4], a5 = p[5], a6 = p[6], a7 = p[7];
        float s = ((a0.x + a0.y + a0.z + a0.w) + (a1.x + a1.y + a1.z + a1.w))
                + ((a2.x + a2.y + a2.z + a2.w) + (a3.x + a3.y + a3.z + a3.w))
                + ((a4.x + a4.y + a4.z + a4.w) + (a5.x + a5.y + a5.z + a5.w))
                + ((a6.x + a6.y + a6.z + a6.w) + (a7.x + a7.y + a7.z + a7.w));
        s += __shfl_xor(s, 1, 64);   // butterfly within the 8-lane group
        s += __shfl_xor(s, 2, 64);
        s += __shfl_xor(s, 4, 64);
        if (sub == 0) tot[b] = s;
    }
    __syncthreads();

    const float v = (t < NBINS) ? tot[t] : 0.0f;
    if (t < 128) {
        float s = v;
        s += __shfl_xor(s, 1, 64);
        s += __shfl_xor(s, 2, 64);
        s += __shfl_xor(s, 4, 64);
        s += __shfl_xor(s, 8, 64);
        s += __shfl_xor(s, 16, 64);
        s += __shfl_xor(s, 32, 64);
        if ((t & 63) == 0) wsum[t >> 6] = s;
    }
    __syncthreads();
    const float total = wsum[0] + wsum[1];

    if (t < NBINS) {
        const float count = v / total;
        out[t] = count;                                   // output 0: count[100]
        const float b0 = 0.05f * (float)t;
        const float b1 = 0.05f * (float)(t + 1);
        const float vol = (4.0f * PI_F / 3.0f) * (b1 * b1 * b1 - b0 * b0 * b0);
        const float V = (4.0f / 3.0f) * PI_F * 125.0f;    // end^3 = 5^3
        out[2 * NBINS + 1 + t] = count * V / vol;         // output 2: rdf[100]
    }
    if (t < NBINS + 1) {
        out[NBINS + t] = 0.05f * (float)t;                // output 1: bins[101]
    }
}

extern "C" void kernel_launch(void* const* d_in, const int* in_sizes, int n_in,
                              void* d_out, int out_size, void* d_ws, size_t ws_size,
                              hipStream_t stream) {
    const float* xyz  = (const float*)d_in[0];
    const float* cell = (const float*)d_in[1];
    float* out = (float*)d_out;
    float* ws  = (float*)d_ws;

    rdf_hist<<<NBLK, 1024, 0, stream>>>(xyz, cell, ws);
    rdf_finalize<<<1, 1024, 0, stream>>>(ws, out);
}